// Round 8
// baseline (2909.710 us; speedup 1.0000x reference)
//
#include <hip/hip_runtime.h>

typedef unsigned long long u64;
typedef unsigned int u32;
typedef unsigned short u16;

#define NB   8
#define NPC  8192
#define SS   2048
#define KK   32
#define CIN  64
#define NQ   (NB*SS)              // 16384
#define POS_OUT_OFF   (NQ*128)
#define BATCH_OUT_OFF (NQ*128 + NQ*3)
#define INF64 0x7ff0000000000000ULL
#define NCELL 512
#define CHUNKS 256                // 32 points per chunk

// Swizzle: logical slot -> physical LDS index. Within chunk c (32 slots,
// 32-float-aligned base) element k sits at k^(c&31): the 32 lanes of a chunk
// touch all 32 banks (conflict-free); bijective within the chunk.
__device__ __forceinline__ u32 swz(u32 p) { return p ^ ((p >> 5) & 31u); }

// ---- f64-key: key = (mind_bits<<32) | (8191-origIdx)<<13 | slot ----------
// mind is always finite when keys are built -> finite positive f64 patterns;
// fmax == exact u64 max; tie-break = smallest original index (ref argmax).

// 64-bit wave max via paired 32-bit DPP (gfx9 row_shr/row_bcast sequence).
__device__ __forceinline__ double wave64_max(double v) {
#define DPP_LVL(ctrl) { \
    int lo = __double2loint(v), hi = __double2hiint(v); \
    int tlo = __builtin_amdgcn_update_dpp(lo, lo, ctrl, 0xf, 0xf, false); \
    int thi = __builtin_amdgcn_update_dpp(hi, hi, ctrl, 0xf, 0xf, false); \
    v = fmax(v, __hiloint2double(thi, tlo)); }
    DPP_LVL(0x111) DPP_LVL(0x112) DPP_LVL(0x114) DPP_LVL(0x118)
    DPP_LVL(0x142) DPP_LVL(0x143)
#undef DPP_LVL
    return v;                       // valid in lane 63
}
// 16-lane (DPP row) max; result valid in lanes 15,31,47,63 (and upper half of each row).
__device__ __forceinline__ double row16_max(double v) {
#define DPP_LVL(ctrl) { \
    int lo = __double2loint(v), hi = __double2hiint(v); \
    int tlo = __builtin_amdgcn_update_dpp(lo, lo, ctrl, 0xf, 0xf, false); \
    int thi = __builtin_amdgcn_update_dpp(hi, hi, ctrl, 0xf, 0xf, false); \
    v = fmax(v, __hiloint2double(thi, tlo)); }
    DPP_LVL(0x111) DPP_LVL(0x112) DPP_LVL(0x114) DPP_LVL(0x118)
#undef DPP_LVL
    return v;
}

// ---------------- Kernel 1: ball-pruned exact farthest point sampling ------
// One block/cloud, 256 thr. Counting-sorted, XOR-swizzled SoA in LDS.
// Per step: A) per-thread chunk-vs-ball(c, sqrt(M)) test + per-wave compact;
// B) point-granular update of active chunks (32 lanes/chunk, bank-clean),
//    chunk key via row16-DPP + shfl_xor(16); skipped chunks keep stale-valid
//    keys; C) per-wave fold of 256 chunk keys -> (ws, M, center).
// Skip exactness: mind[p] <= M for all p; skip iff lb2*0.99999 >= M  =>
// computed d2 >= lb2*(1-4e-6) > mind[p]  =>  update provably no-op.
__global__ __launch_bounds__(256) void fps_kernel(const float* __restrict__ pos,
                                                  float* __restrict__ out)
{
    __shared__ float sxp[NPC], syp[NPC], szp[NPC], smind[NPC];
    __shared__ u16 sid[NPC];
    __shared__ u32 cs[NCELL];
    __shared__ u32 cnt_hist[1024];       // init: cnt[512] u32; loop: hist u16[2048]
    __shared__ double ckey[CHUNKS];
    __shared__ u16 list[4][64];
    __shared__ u32 na[4];
    __shared__ u32 ws0_sh;

    const int tid  = threadIdx.x;
    const int wid  = tid >> 6;
    const int lane = tid & 63;
    const int cloud = blockIdx.x;
    const float* cp = pos + (size_t)cloud * (NPC*3);
    const float finf = __int_as_float(0x7f800000);

    // ---- init: histogram -> scan -> swizzled scatter (R7-proven pattern) ----
    u32* cnt = cnt_hist;
    for (int c = tid; c < NCELL; c += 256) cnt[c] = 0;
    __syncthreads();
    for (int i = tid; i < NPC; i += 256) {
        float x = cp[i*3+0], y = cp[i*3+1], z = cp[i*3+2];
        int cx = (int)(x*8.0f); cx = cx>7?7:cx;      // pos in [0,1)
        int cy = (int)(y*8.0f); cy = cy>7?7:cy;
        int cz = (int)(z*8.0f); cz = cz>7?7:cz;
        atomicAdd(&cnt[(cx<<6)|(cy<<3)|cz], 1u);
    }
    __syncthreads();
    {   // inclusive Hillis-Steele scan of cnt into cs; cnt := exclusive starts
        int c0 = tid, c1 = tid + 256;
        cs[c0] = cnt[c0]; cs[c1] = cnt[c1];
        __syncthreads();
        for (int off = 1; off < NCELL; off <<= 1) {
            u32 v0 = cs[c0] + ((c0 >= off) ? cs[c0-off] : 0u);
            u32 v1 = cs[c1] + ((c1 >= off) ? cs[c1-off] : 0u);
            __syncthreads();
            cs[c0] = v0; cs[c1] = v1;
            __syncthreads();
        }
        cnt[c0] = cs[c0] - cnt[c0];
        cnt[c1] = cs[c1] - cnt[c1];
    }
    __syncthreads();
    for (int i = tid; i < NPC; i += 256) {
        float x = cp[i*3+0], y = cp[i*3+1], z = cp[i*3+2];
        int cx = (int)(x*8.0f); cx = cx>7?7:cx;
        int cy = (int)(y*8.0f); cy = cy>7?7:cy;
        int cz = (int)(z*8.0f); cz = cz>7?7:cz;
        u32 slot = atomicAdd(&cnt[(cx<<6)|(cy<<3)|cz], 1u);
        u32 ph = swz(slot);
        sxp[ph] = x; syp[ph] = y; szp[ph] = z;
        sid[ph] = (u16)i;
        smind[ph] = finf;
        if (i == 0) ws0_sh = slot;       // logical slot of original point 0
    }
    __syncthreads();

    // ---- per-thread chunk bbox (registers; chunk tid = phys slots tid*32..) --
    float bxl, bxh, byl, byh, bzl, bzh;
    {
        int base = tid * 32;
        bxl = bxh = sxp[base]; byl = byh = syp[base]; bzl = bzh = szp[base];
        for (int k = 1; k < 32; ++k) {
            float x = sxp[base+k], y = syp[base+k], z = szp[base+k];
            bxl = fminf(bxl, x); bxh = fmaxf(bxh, x);
            byl = fminf(byl, y); byh = fmaxf(byh, y);
            bzl = fminf(bzl, z); bzh = fmaxf(bzh, z);
        }
    }

    // ---- main loop ----
    u16* hist = (u16*)cnt_hist;
    u32 ws = ws0_sh;
    float M = finf;
    u32 wp0 = swz(ws);
    float ccx = sxp[wp0], ccy = syp[wp0], ccz = szp[wp0];

    for (int s = 0; s < SS; ++s) {
        if (tid == 0) hist[s] = (u16)ws;
        // A: chunk-vs-ball test (conservative margin: never skips a live chunk)
        float lx = fmaxf(fmaxf(bxl - ccx, ccx - bxh), 0.0f);
        float ly = fmaxf(fmaxf(byl - ccy, ccy - byh), 0.0f);
        float lz = fmaxf(fmaxf(bzl - ccz, ccz - bzh), 0.0f);
        float lb2 = lx*lx + ly*ly + lz*lz;
        bool act = (lb2 * 0.99999f) < M;
        u64 mk = __ballot(act);
        if (act) list[wid][__popcll(mk & ((1ull<<lane)-1ull))] = (u16)tid;
        if (lane == 0) na[wid] = (u32)__popcll(mk);
        __syncthreads();                 // bar1

        // B: point-granular update of active chunks (32 lanes per chunk)
        u32 n0 = na[0], n1 = na[1], n2 = na[2], n3 = na[3];
        u32 P1 = n0, P2 = n0+n1, P3 = P2+n2;
        u32 tpts = (P3 + n3) << 5;
        for (u32 h = tid; h < tpts; h += 256) {
            u32 ci = h >> 5, k = h & 31;
            u32 w = (ci>=P1) + (ci>=P2) + (ci>=P3);
            u32 idx = ci - (w==0 ? 0u : (w==1 ? P1 : (w==2 ? P2 : P3)));
            u32 chunk = list[w][idx];
            u32 p  = (chunk << 5) | k;                // logical slot
            u32 ph = (chunk << 5) | (k ^ (chunk & 31u));
            float dx = __fsub_rn(sxp[ph], ccx);
            float dy = __fsub_rn(syp[ph], ccy);
            float dz = __fsub_rn(szp[ph], ccz);
            float d2 = __fadd_rn(__fadd_rn(__fmul_rn(dx,dx), __fmul_rn(dy,dy)),
                                 __fmul_rn(dz,dz));
            float m = fminf(smind[ph], d2);
            smind[ph] = m;
            u32 low = ((8191u - (u32)sid[ph]) << 13) | p;
            double fk = __hiloint2double((int)__float_as_uint(m), (int)low);
            fk = row16_max(fk);
            double o = __shfl_xor(fk, 16);
            fk = fmax(fk, o);
            if ((lane & 31) == 31) ckey[chunk] = fk;  // group max -> chunk key
        }
        __syncthreads();                 // bar2

        // C: per-wave fold of all 256 chunk keys -> winner (slot), M, center
        double k0 = fmax(ckey[lane      ], ckey[lane + 64 ]);
        double k1 = fmax(ckey[lane + 128], ckey[lane + 192]);
        double kf = wave64_max(fmax(k0, k1));
        int klo = __builtin_amdgcn_readlane(__double2loint(kf), 63);
        int khi = __builtin_amdgcn_readlane(__double2hiint(kf), 63);
        ws = (u32)klo & 8191u;
        M  = __uint_as_float((u32)khi);
        u32 wph = swz(ws);
        ccx = sxp[wph]; ccy = syp[wph]; ccz = szp[wph];
    }
    __syncthreads();

    // ---- outputs ----
    float* qout = out + POS_OUT_OFF   + (size_t)cloud * SS * 3;
    float* bout = out + BATCH_OUT_OFF + (size_t)cloud * SS;
    for (int s2 = tid; s2 < SS; s2 += 256) {
        u32 wph = swz((u32)hist[s2]);
        qout[s2*3+0] = sxp[wph];
        qout[s2*3+1] = syp[wph];
        qout[s2*3+2] = szp[wph];
        bout[s2] = (float)cloud;
    }
}

// ---------------- Kernel 2: radius / 32 smallest-d2 selection ---------------
// Global-direct scan (cloud is L2-resident across the 64 blocks sharing it),
// ballot-compacted candidates in LDS, f64-key min extraction.
#define CAND_MAX 640
__global__ __launch_bounds__(256) void radius_kernel(const float* __restrict__ pos,
                                                     const float* __restrict__ out,
                                                     int* __restrict__ nidx,
                                                     int* __restrict__ ncnt)
{
    __shared__ u64 cand[4][CAND_MAX];
    const int tid  = threadIdx.x;
    const int wid  = tid >> 6;
    const int lane = tid & 63;
    const float R2 = (float)(0.2 * 0.2);        // float32(0.04) = 0x3D23D70A
    const float* qpos = out + POS_OUT_OFF;
    u64* cw = cand[wid];

    for (int qq = 0; qq < 4; ++qq) {
        const int q     = blockIdx.x*16 + wid*4 + qq;
        const int cloud = q >> 11;
        const float* cp = pos + (size_t)cloud * (NPC*3);
        float qx = qpos[q*3+0], qy = qpos[q*3+1], qz = qpos[q*3+2];

        int m = 0;
        for (int c = 0; c < NPC/64; ++c) {
            int j = c*64 + lane;
            float dx = __fsub_rn(cp[j*3+0], qx);
            float dy = __fsub_rn(cp[j*3+1], qy);
            float dz = __fsub_rn(cp[j*3+2], qz);
            float d2 = __fadd_rn(__fadd_rn(__fmul_rn(dx,dx), __fmul_rn(dy,dy)), __fmul_rn(dz,dz));
            bool in = (d2 <= R2);
            u64 mk = __ballot(in);
            if (in) {
                int p = m + __popcll(mk & ((1ull << lane) - 1ull));
                if (p < CAND_MAX) cw[p] = ((u64)__float_as_uint(d2) << 32) | (u32)j;
            }
            m += __popcll(mk);
        }
        if (m > CAND_MAX) m = CAND_MAX;

        double kk[10];
        #pragma unroll
        for (int t = 0; t < 10; ++t) {
            int p = t*64 + lane;
            kk[t] = (p < m) ? __longlong_as_double((long long)cw[p])
                            : __longlong_as_double((long long)INF64);
        }
        int cq = (m < KK) ? m : KK;
        int* nq = nidx + (size_t)q * KK;
        int j0 = 0;
        #pragma unroll 1
        for (int r = 0; r < KK; ++r) {
            double lmin = kk[0];
            #pragma unroll
            for (int t = 1; t < 10; ++t) lmin = fmin(lmin, kk[t]);
            #pragma unroll
            for (int off = 32; off >= 1; off >>= 1)
                lmin = fmin(lmin, __shfl_xor(lmin, off));
            u64 lb = (u64)__double_as_longlong(lmin);
            int j = (int)(u32)lb;
            if (r == 0) j0 = j;                 // center itself (d2=0) is first
            if (lane == 0) nq[r] = (lb == INF64) ? j0 : j;
            #pragma unroll
            for (int t = 0; t < 10; ++t)
                if ((u64)__double_as_longlong(kk[t]) == lb)
                    kk[t] = __longlong_as_double((long long)INF64);
        }
        if (lane == 0) ncnt[q] = cq;
    }
}

// ---------------- Kernel 3: gather + 3-layer MLP + masked max ---------------
// Weights/biases read straight from global with wave-uniform indices ->
// compiler emits s_load broadcasts (no LDS pipe pressure). feat in padded LDS.
__global__ __launch_bounds__(256) void mlp_kernel(const float* __restrict__ x,
                                                  const float* __restrict__ pos,
                                                  const float* __restrict__ W1, const float* __restrict__ b1,
                                                  const float* __restrict__ W2, const float* __restrict__ b2,
                                                  const float* __restrict__ W3, const float* __restrict__ b3,
                                                  const int* __restrict__ nidx, const int* __restrict__ ncnt,
                                                  float* __restrict__ out)
{
    __shared__ float flds[256*69];

    const int tid   = threadIdx.x;
    const int q     = blockIdx.x * 8 + (tid >> 5);
    const int slot  = tid & 31;
    const int cloud = q >> 11;
    const int j     = nidx[q*KK + slot];
    const bool valid = slot < ncnt[q];
    const size_t row = (size_t)cloud * NPC + (size_t)j;

    const float* qp = out + POS_OUT_OFF + (size_t)q*3;
    float qx = qp[0], qy = qp[1], qz = qp[2];

    float* myf = &flds[tid*69];
    {
        const float4* xr = (const float4*)(x + row*CIN);
        #pragma unroll
        for (int i = 0; i < 16; ++i) {
            float4 v = xr[i];
            myf[i*4+0]=v.x; myf[i*4+1]=v.y; myf[i*4+2]=v.z; myf[i*4+3]=v.w;
        }
        myf[64] = __fsub_rn(pos[row*3+0], qx);
        myf[65] = __fsub_rn(pos[row*3+1], qy);
        myf[66] = __fsub_rn(pos[row*3+2], qz);
    }
    // each thread reads only its own flds region: no barrier needed

    float acc[64];
    // ----- layer 1: 67 -> 64, relu -----
    #pragma unroll
    for (int o = 0; o < 64; ++o) acc[o] = b1[o];
    #pragma unroll 2
    for (int i = 0; i < 67; ++i) {
        float f = myf[i];
        const float4* wr = (const float4*)(W1 + i*64);
        #pragma unroll
        for (int o4 = 0; o4 < 16; ++o4) {
            float4 wv = wr[o4];
            acc[o4*4+0] = fmaf(f, wv.x, acc[o4*4+0]);
            acc[o4*4+1] = fmaf(f, wv.y, acc[o4*4+1]);
            acc[o4*4+2] = fmaf(f, wv.z, acc[o4*4+2]);
            acc[o4*4+3] = fmaf(f, wv.w, acc[o4*4+3]);
        }
    }
    #pragma unroll
    for (int o = 0; o < 64; ++o) myf[o] = fmaxf(acc[o], 0.0f);

    // ----- layer 2: 64 -> 64, relu -----
    #pragma unroll
    for (int o = 0; o < 64; ++o) acc[o] = b2[o];
    #pragma unroll 2
    for (int i = 0; i < 64; ++i) {
        float f = myf[i];
        const float4* wr = (const float4*)(W2 + i*64);
        #pragma unroll
        for (int o4 = 0; o4 < 16; ++o4) {
            float4 wv = wr[o4];
            acc[o4*4+0] = fmaf(f, wv.x, acc[o4*4+0]);
            acc[o4*4+1] = fmaf(f, wv.y, acc[o4*4+1]);
            acc[o4*4+2] = fmaf(f, wv.z, acc[o4*4+2]);
            acc[o4*4+3] = fmaf(f, wv.w, acc[o4*4+3]);
        }
    }
    #pragma unroll
    for (int o = 0; o < 64; ++o) myf[o] = fmaxf(acc[o], 0.0f);

    // ----- layer 3: 64 -> 128 (two halves), mask, max over 32 slots -----
    float* orow = out + (size_t)q*128;
    const float NEGINF = __int_as_float(0xff800000);
    for (int h = 0; h < 2; ++h) {
        #pragma unroll
        for (int o = 0; o < 64; ++o) acc[o] = b3[h*64 + o];
        const float* w3h = W3 + h*64;
        #pragma unroll 2
        for (int i = 0; i < 64; ++i) {
            float f = myf[i];
            const float4* wr = (const float4*)(w3h + i*128);
            #pragma unroll
            for (int o4 = 0; o4 < 16; ++o4) {
                float4 wv = wr[o4];
                acc[o4*4+0] = fmaf(f, wv.x, acc[o4*4+0]);
                acc[o4*4+1] = fmaf(f, wv.y, acc[o4*4+1]);
                acc[o4*4+2] = fmaf(f, wv.z, acc[o4*4+2]);
                acc[o4*4+3] = fmaf(f, wv.w, acc[o4*4+3]);
            }
        }
        #pragma unroll
        for (int o = 0; o < 64; ++o) if (!valid) acc[o] = NEGINF;
        #pragma unroll
        for (int off = 16; off >= 1; off >>= 1) {
            #pragma unroll
            for (int o = 0; o < 64; ++o) acc[o] = fmaxf(acc[o], __shfl_xor(acc[o], off));
        }
        if (slot == 0) {
            #pragma unroll
            for (int o = 0; o < 64; o += 4) {
                float4 v = make_float4(acc[o], acc[o+1], acc[o+2], acc[o+3]);
                *(float4*)&orow[h*64+o] = v;
            }
        }
    }
}

// ------------------------------- launcher -----------------------------------
extern "C" void kernel_launch(void* const* d_in, const int* in_sizes, int n_in,
                              void* d_out, int out_size, void* d_ws, size_t ws_size,
                              hipStream_t stream) {
    const float* x   = (const float*)d_in[0];
    const float* pos = (const float*)d_in[1];
    // d_in[2]=batch (implicit), d_in[3]=num_samples (K=32 hardcoded)
    const float* W1 = (const float*)d_in[4];
    const float* b1 = (const float*)d_in[5];
    const float* W2 = (const float*)d_in[6];
    const float* b2 = (const float*)d_in[7];
    const float* W3 = (const float*)d_in[8];
    const float* b3 = (const float*)d_in[9];
    float* out = (float*)d_out;

    int* nidx = (int*)d_ws;                  // NQ*KK ints (2 MiB)
    int* ncnt = nidx + (size_t)NQ*KK;        // NQ ints

    hipLaunchKernelGGL(fps_kernel,    dim3(NB),      dim3(256), 0, stream, pos, out);
    hipLaunchKernelGGL(radius_kernel, dim3(NQ/16),   dim3(256), 0, stream, pos, out, nidx, ncnt);
    hipLaunchKernelGGL(mlp_kernel,    dim3(NQ/8),    dim3(256), 0, stream,
                       x, pos, W1, b1, W2, b2, W3, b3, nidx, ncnt, out);
}